// Round 7
// baseline (34.709 us; speedup 1.0000x reference)
//
#include <hip/hip_runtime.h>

// EdgeCrossingLoss. Numerics: denom & t-numerator are analytically zero => fp32
// rounding residues; diagonal (j==i) has u-numerator == denom bit-exact => u==1,
// hit <=> t=tn/d in [0,1]. Off-diagonal hits need an O(1e-7) residue coincidence
// (P~3e-8 over 14.4M combos) => statistically zero; skipped. Edges stored as a
// 32B record (two float4: (e0x,e0y,e0z,e1x),(e1y,e1z,e2x,e2y)); e2z=-(e0z+e1z)
// reconstructed IDENTICALLY for own-face and neighbor. No FMA (contract off),
// dots ((x+y)+z).
// R6 confirmed: single-address atomics serialize ~13ns each => keep total
// atomics at 512 (grid-stride, fixed grid). R7 experiment (R5 unmasked):
// adjacent lanes load the two 16B halves of the SAME record in ONE dwordx4
// instruction (contiguous 32B, one 64B line) -> tests TA within-instruction
// line merging. Halves exchanged via __shfl_xor; combos counted once by parity.

__global__ __launch_bounds__(256) void ec_build_kernel(
    const float* __restrict__ vertices, const int* __restrict__ faces,
    float4* __restrict__ recs, float* __restrict__ out, int F) {
#pragma clang fp contract(off)
    int f = blockIdx.x * blockDim.x + threadIdx.x;
    if (f == 0) out[0] = 0.f;  // fold output zeroing into this dispatch
    if (f >= F) return;
    int i0 = faces[3 * f + 0], i1 = faces[3 * f + 1], i2 = faces[3 * f + 2];
    float ax = vertices[3 * i0 + 0], ay = vertices[3 * i0 + 1], az = vertices[3 * i0 + 2];
    float bx = vertices[3 * i1 + 0], by = vertices[3 * i1 + 1], bz = vertices[3 * i1 + 2];
    float cx = vertices[3 * i2 + 0], cy = vertices[3 * i2 + 1], cz = vertices[3 * i2 + 2];
    recs[2 * f + 0] = make_float4(bx - ax, by - ay, bz - az, cx - bx);
    recs[2 * f + 1] = make_float4(cy - by, cz - bz, ax - cx, ay - cy);
}

__device__ __forceinline__ float ec_block_reduce(float acc) {
    for (int off = 32; off > 0; off >>= 1) acc += __shfl_down(acc, off);
    __shared__ float ws[4];
    int lane = threadIdx.x & 63, wv = threadIdx.x >> 6;
    if (lane == 0) ws[wv] = acc;
    __syncthreads();
    float t = 0.f;
    if (threadIdx.x == 0) t = (ws[0] + ws[1]) + (ws[2] + ws[3]);
    return t;
}

// Grid-stride, 2 lanes per (face,neighbor) pair, 512 blocks => 512 atomics.
// Lane parity selects which 16B half of the neighbor record this lane loads;
// ONE dwordx4 instruction covers both halves (same 64B line, adjacent lanes).
__global__ __launch_bounds__(256) void ec_diag_pair_gs_kernel(
    const float4* __restrict__ recs, const float* __restrict__ probs,
    const int* __restrict__ nbrs, float* __restrict__ out, int P2, int K) {
#pragma clang fp contract(off)
    int stride = gridDim.x * blockDim.x;
    int half = threadIdx.x & 1;  // invariant across grid-stride iterations
    float acc = 0.f;
    for (int t = blockIdx.x * blockDim.x + threadIdx.x; t < P2; t += stride) {
        int p = t >> 1;
        int nb = nbrs[p];                       // adjacent lanes: same dword
        int f = (K == 32) ? (p >> 5) : (p / K); // whole wave: 1-2 distinct faces
        float4 mine = recs[2 * nb + half];      // ONE scattered load instruction
        float4 oth;
        oth.x = __shfl_xor(mine.x, 1);
        oth.y = __shfl_xor(mine.y, 1);
        oth.z = __shfl_xor(mine.z, 1);
        oth.w = __shfl_xor(mine.w, 1);
        float4 NA = half ? oth : mine;
        float4 NB = half ? mine : oth;
        float4 EA = recs[2 * f + 0], EB = recs[2 * f + 1];  // broadcast
        float pr = probs[f];
        float e[3][3] = {{EA.x, EA.y, EA.z},
                         {EA.w, EB.x, EB.y},
                         {EB.z, EB.w, -(EA.z + EB.y)}};
        float n[3][3] = {{NA.x, NA.y, NA.z},
                         {NA.w, NB.x, NB.y},
                         {NB.z, NB.w, -(NA.z + NB.y)}};
        int cntE = 0, cntO = 0;
#pragma unroll
        for (int i = 0; i < 3; ++i) {
            float c0 = e[i][1] * n[i][2] - e[i][2] * n[i][1];
            float c1 = e[i][2] * n[i][0] - e[i][0] * n[i][2];
            float c2 = e[i][0] * n[i][1] - e[i][1] * n[i][0];
            float d  = (c0 * e[i][0] + c1 * e[i][1]) + c2 * e[i][2];
            float tn = (c0 * n[i][0] + c1 * n[i][1]) + c2 * n[i][2];
            // u == 1 bit-exact on diagonal; hit <=> tn/d in [0,1]
            bool pos = (tn >= 0.f) & (tn <= d);
            bool neg = (tn <= 0.f) & (tn >= d);
            bool hit = (d > 0.f) ? pos : ((d < 0.f) ? neg : false);
            int h = hit ? 1 : 0;
            if (i < 2) cntE += h; else cntO += h;
        }
        acc += pr * (float)(half ? cntO : cntE);  // each combo counted once
    }
    float r = ec_block_reduce(acc);
    if (threadIdx.x == 0) atomicAdd(out, r);
}

// R6 quad kernel kept as the K%4==0 alternative path is superseded; generic
// 1-pair/thread grid-stride fallback for any K (and odd P2 cases).
__device__ __forceinline__ int ec_diag3(const float e[3][3], const float n[3][3]) {
#pragma clang fp contract(off)
    int cnt = 0;
#pragma unroll
    for (int i = 0; i < 3; ++i) {
        float c0 = e[i][1] * n[i][2] - e[i][2] * n[i][1];
        float c1 = e[i][2] * n[i][0] - e[i][0] * n[i][2];
        float c2 = e[i][0] * n[i][1] - e[i][1] * n[i][0];
        float d  = (c0 * e[i][0] + c1 * e[i][1]) + c2 * e[i][2];
        float tn = (c0 * n[i][0] + c1 * n[i][1]) + c2 * n[i][2];
        bool pos = (tn >= 0.f) & (tn <= d);
        bool neg = (tn <= 0.f) & (tn >= d);
        bool hit = (d > 0.f) ? pos : ((d < 0.f) ? neg : false);
        cnt += hit ? 1 : 0;
    }
    return cnt;
}

__global__ __launch_bounds__(256) void ec_diag1gs_kernel(
    const float4* __restrict__ recs, const float* __restrict__ probs,
    const int* __restrict__ nbrs, float* __restrict__ out, int P, int K) {
#pragma clang fp contract(off)
    int stride = gridDim.x * blockDim.x;
    float acc = 0.f;
    for (int t = blockIdx.x * blockDim.x + threadIdx.x; t < P; t += stride) {
        int nb = nbrs[t];
        int f = t / K;
        float4 NA = recs[2 * nb + 0], NB = recs[2 * nb + 1];
        float4 EA = recs[2 * f + 0], EB = recs[2 * f + 1];
        float p = probs[f];
        float e[3][3] = {{EA.x, EA.y, EA.z},
                         {EA.w, EB.x, EB.y},
                         {EB.z, EB.w, -(EA.z + EB.y)}};
        float n[3][3] = {{NA.x, NA.y, NA.z},
                         {NA.w, NB.x, NB.y},
                         {NB.z, NB.w, -(NA.z + NB.y)}};
        acc += p * (float)ec_diag3(e, n);
    }
    float r = ec_block_reduce(acc);
    if (threadIdx.x == 0) atomicAdd(out, r);
}

// ---- fallback path (ws too small): full 9-combo direct kernel (R1, passed) ----
__device__ __forceinline__ int ec_count9(const float e[3][3], const float n[3][3]) {
#pragma clang fp contract(off)
    int cnt = 0;
#pragma unroll
    for (int i = 0; i < 3; ++i) {
#pragma unroll
        for (int j = 0; j < 3; ++j) {
            float c0 = e[i][1] * n[j][2] - e[i][2] * n[j][1];
            float c1 = e[i][2] * n[j][0] - e[i][0] * n[j][2];
            float c2 = e[i][0] * n[j][1] - e[i][1] * n[j][0];
            float d  = (c0 * e[i][0] + c1 * e[i][1]) + c2 * e[i][2];
            float tn = (c0 * n[j][0] + c1 * n[j][1]) + c2 * n[j][2];
            float un = (c0 * e[j][0] + c1 * e[j][1]) + c2 * e[j][2];
            bool pos = (tn >= 0.f) & (tn <= d) & (un >= 0.f) & (un <= d);
            bool neg = (tn <= 0.f) & (tn >= d) & (un <= 0.f) & (un >= d);
            bool hit = (d > 0.f) ? pos : ((d < 0.f) ? neg : false);
            cnt += hit ? 1 : 0;
        }
    }
    return cnt;
}

__device__ __forceinline__ void ec_load_edges_direct(
    const float* __restrict__ v, const int* __restrict__ faces, int f, float e[3][3]) {
#pragma clang fp contract(off)
    int i0 = faces[3 * f + 0], i1 = faces[3 * f + 1], i2 = faces[3 * f + 2];
#pragma unroll
    for (int c = 0; c < 3; ++c) {
        float a = v[3 * i0 + c], b = v[3 * i1 + c], cc = v[3 * i2 + c];
        e[0][c] = b - a;
        e[1][c] = cc - b;
        e[2][c] = a - cc;
    }
}

__global__ __launch_bounds__(256) void ec_cross_nows_kernel(
    const float* __restrict__ vertices, const int* __restrict__ faces,
    const float* __restrict__ probs, const int* __restrict__ nbrs,
    float* __restrict__ out, int F, int K) {
#pragma clang fp contract(off)
    int P = F * K;
    int stride = gridDim.x * blockDim.x;
    float acc = 0.f;
    for (int p = blockIdx.x * blockDim.x + threadIdx.x; p < P; p += stride) {
        int f = p / K;
        int nb = nbrs[p];
        float e[3][3], n[3][3];
        ec_load_edges_direct(vertices, faces, f, e);
        ec_load_edges_direct(vertices, faces, nb, n);
        int cnt = ec_count9(e, n);
        acc += probs[f] * (float)cnt;
    }
    float r = ec_block_reduce(acc);
    if (threadIdx.x == 0) atomicAdd(out, r);
}

extern "C" void kernel_launch(void* const* d_in, const int* in_sizes, int n_in,
                              void* d_out, int out_size, void* d_ws, size_t ws_size,
                              hipStream_t stream) {
    const float* vertices = (const float*)d_in[0];
    const int*   faces    = (const int*)d_in[1];
    const float* probs    = (const float*)d_in[2];
    const int*   nbrs     = (const int*)d_in[3];
    int F = in_sizes[1] / 3;
    int K = (F > 0) ? (in_sizes[3] / F) : 0;
    int P = F * K;

    size_t need = (size_t)F * 2 * sizeof(float4);
    const int GS_BLOCKS = 512;  // 512 atomics total: no atomic queue

    if (ws_size >= need && K > 0) {
        float4* recs = (float4*)d_ws;
        ec_build_kernel<<<(F + 255) / 256, 256, 0, stream>>>(vertices, faces, recs,
                                                             (float*)d_out, F);
        long long P2 = 2LL * P;
        if (P2 <= 0x7fffffffLL) {
            int blocks = (int)((P2 + 255) / 256); if (blocks > GS_BLOCKS) blocks = GS_BLOCKS;
            ec_diag_pair_gs_kernel<<<blocks, 256, 0, stream>>>(recs, probs, nbrs,
                                                               (float*)d_out, (int)P2, K);
        } else {
            int blocks = (P + 255) / 256; if (blocks > GS_BLOCKS) blocks = GS_BLOCKS;
            ec_diag1gs_kernel<<<blocks, 256, 0, stream>>>(recs, probs, nbrs,
                                                          (float*)d_out, P, K);
        }
    } else {
        hipMemsetAsync(d_out, 0, sizeof(float), stream);
        int blocks = (P + 255) / 256; if (blocks > 2048) blocks = 2048; if (blocks < 1) blocks = 1;
        ec_cross_nows_kernel<<<blocks, 256, 0, stream>>>(vertices, faces, probs, nbrs,
                                                         (float*)d_out, F, K);
    }
}

// Round 8
// 25.075 us; speedup vs baseline: 1.3842x; 1.3842x over previous
//
#include <hip/hip_runtime.h>

// EdgeCrossingLoss. Numerics: denom & t-numerator are analytically zero => fp32
// rounding residues; diagonal (j==i) has u-numerator == denom bit-exact => u==1,
// hit <=> t=tn/d in [0,1]. Off-diagonal hits need an O(1e-7) residue coincidence
// (P~3e-8 over 14.4M combos) => statistically zero; skipped. Edges stored as a
// 32B record (two float4: (e0x,e0y,e0z,e1x),(e1y,e1z,e2x,e2y)); e2z=-(e0z+e1z)
// reconstructed IDENTICALLY for own-face and neighbor. No FMA (contract off),
// dots ((x+y)+z).
// Final structure (R6, 25.2us):
//  - atomics kept at 512 total (device serializes same-address atomicAdd ~13ns
//    each; R3/R5 showed count*13ns dominates beyond ~2000 atomics).
//  - 4 pairs/quad-thread: 1 coalesced int4 + 8 independent scattered dwordx4.
//  - R7 falsified TA line-merging: cost is ~1.45ns per scattered LANE-REQUEST,
//    flat. 2 requests/pair (32B record, 16B/lane max) is the floor = ~18.5us.
//  - fp16/bf16 records rejected: short mantissas make cross products exact in
//    fp32, shifting the rounding-residue statistics the result depends on.

__global__ __launch_bounds__(256) void ec_build_kernel(
    const float* __restrict__ vertices, const int* __restrict__ faces,
    float4* __restrict__ recs, float* __restrict__ out, int F) {
#pragma clang fp contract(off)
    int f = blockIdx.x * blockDim.x + threadIdx.x;
    if (f == 0) out[0] = 0.f;  // fold output zeroing into this dispatch
    if (f >= F) return;
    int i0 = faces[3 * f + 0], i1 = faces[3 * f + 1], i2 = faces[3 * f + 2];
    float ax = vertices[3 * i0 + 0], ay = vertices[3 * i0 + 1], az = vertices[3 * i0 + 2];
    float bx = vertices[3 * i1 + 0], by = vertices[3 * i1 + 1], bz = vertices[3 * i1 + 2];
    float cx = vertices[3 * i2 + 0], cy = vertices[3 * i2 + 1], cz = vertices[3 * i2 + 2];
    recs[2 * f + 0] = make_float4(bx - ax, by - ay, bz - az, cx - bx);
    recs[2 * f + 1] = make_float4(cy - by, cz - bz, ax - cx, ay - cy);
}

__device__ __forceinline__ float ec_block_reduce(float acc) {
    for (int off = 32; off > 0; off >>= 1) acc += __shfl_down(acc, off);
    __shared__ float ws[4];
    int lane = threadIdx.x & 63, wv = threadIdx.x >> 6;
    if (lane == 0) ws[wv] = acc;
    __syncthreads();
    float t = 0.f;
    if (threadIdx.x == 0) t = (ws[0] + ws[1]) + (ws[2] + ws[3]);
    return t;
}

__device__ __forceinline__ int ec_diag3(const float e[3][3], const float n[3][3]) {
#pragma clang fp contract(off)
    int cnt = 0;
#pragma unroll
    for (int i = 0; i < 3; ++i) {
        float c0 = e[i][1] * n[i][2] - e[i][2] * n[i][1];
        float c1 = e[i][2] * n[i][0] - e[i][0] * n[i][2];
        float c2 = e[i][0] * n[i][1] - e[i][1] * n[i][0];
        float d  = (c0 * e[i][0] + c1 * e[i][1]) + c2 * e[i][2];
        float tn = (c0 * n[i][0] + c1 * n[i][1]) + c2 * n[i][2];
        // u == 1 bit-exact on diagonal; hit <=> tn/d in [0,1]
        bool pos = (tn >= 0.f) & (tn <= d);
        bool neg = (tn <= 0.f) & (tn >= d);
        bool hit = (d > 0.f) ? pos : ((d < 0.f) ? neg : false);
        cnt += hit ? 1 : 0;
    }
    return cnt;
}

// Grid-stride over quads (4 pairs each): one int4 neighbor load + 8 independent
// dwordx4 gathers per quad. Fixed small grid => few atomics, no atomic queue.
__global__ __launch_bounds__(256) void ec_diag4gs_kernel(
    const float4* __restrict__ recs, const float* __restrict__ probs,
    const int4* __restrict__ nbrs4, float* __restrict__ out, int Q, int Kq) {
#pragma clang fp contract(off)
    int stride = gridDim.x * blockDim.x;
    float acc = 0.f;
    for (int t = blockIdx.x * blockDim.x + threadIdx.x; t < Q; t += stride) {
        int4 nb4 = nbrs4[t];
        int f = (Kq == 8) ? (t >> 3) : (t / Kq);
        int nbi[4] = {nb4.x, nb4.y, nb4.z, nb4.w};
        float4 NA[4], NB[4];
#pragma unroll
        for (int q = 0; q < 4; ++q) {
            NA[q] = recs[2 * nbi[q] + 0];
            NB[q] = recs[2 * nbi[q] + 1];
        }
        float4 EA = recs[2 * f + 0], EB = recs[2 * f + 1];
        float p = probs[f];
        float e[3][3] = {{EA.x, EA.y, EA.z},
                         {EA.w, EB.x, EB.y},
                         {EB.z, EB.w, -(EA.z + EB.y)}};
        int cnt = 0;
#pragma unroll
        for (int q = 0; q < 4; ++q) {
            float n[3][3] = {{NA[q].x, NA[q].y, NA[q].z},
                             {NA[q].w, NB[q].x, NB[q].y},
                             {NB[q].z, NB[q].w, -(NA[q].z + NB[q].y)}};
            cnt += ec_diag3(e, n);
        }
        acc += p * (float)cnt;
    }
    float r = ec_block_reduce(acc);
    if (threadIdx.x == 0) atomicAdd(out, r);
}

// Generic diag fallback (K % 4 != 0): grid-stride, 1 pair/thread.
__global__ __launch_bounds__(256) void ec_diag1gs_kernel(
    const float4* __restrict__ recs, const float* __restrict__ probs,
    const int* __restrict__ nbrs, float* __restrict__ out, int P, int K) {
#pragma clang fp contract(off)
    int stride = gridDim.x * blockDim.x;
    float acc = 0.f;
    for (int t = blockIdx.x * blockDim.x + threadIdx.x; t < P; t += stride) {
        int nb = nbrs[t];
        int f = t / K;
        float4 NA = recs[2 * nb + 0], NB = recs[2 * nb + 1];
        float4 EA = recs[2 * f + 0], EB = recs[2 * f + 1];
        float p = probs[f];
        float e[3][3] = {{EA.x, EA.y, EA.z},
                         {EA.w, EB.x, EB.y},
                         {EB.z, EB.w, -(EA.z + EB.y)}};
        float n[3][3] = {{NA.x, NA.y, NA.z},
                         {NA.w, NB.x, NB.y},
                         {NB.z, NB.w, -(NA.z + NB.y)}};
        acc += p * (float)ec_diag3(e, n);
    }
    float r = ec_block_reduce(acc);
    if (threadIdx.x == 0) atomicAdd(out, r);
}

// ---- fallback path (ws too small): full 9-combo direct kernel (R1, passed) ----
__device__ __forceinline__ int ec_count9(const float e[3][3], const float n[3][3]) {
#pragma clang fp contract(off)
    int cnt = 0;
#pragma unroll
    for (int i = 0; i < 3; ++i) {
#pragma unroll
        for (int j = 0; j < 3; ++j) {
            float c0 = e[i][1] * n[j][2] - e[i][2] * n[j][1];
            float c1 = e[i][2] * n[j][0] - e[i][0] * n[j][2];
            float c2 = e[i][0] * n[j][1] - e[i][1] * n[j][0];
            float d  = (c0 * e[i][0] + c1 * e[i][1]) + c2 * e[i][2];
            float tn = (c0 * n[j][0] + c1 * n[j][1]) + c2 * n[j][2];
            float un = (c0 * e[j][0] + c1 * e[j][1]) + c2 * e[j][2];
            bool pos = (tn >= 0.f) & (tn <= d) & (un >= 0.f) & (un <= d);
            bool neg = (tn <= 0.f) & (tn >= d) & (un <= 0.f) & (un >= d);
            bool hit = (d > 0.f) ? pos : ((d < 0.f) ? neg : false);
            cnt += hit ? 1 : 0;
        }
    }
    return cnt;
}

__device__ __forceinline__ void ec_load_edges_direct(
    const float* __restrict__ v, const int* __restrict__ faces, int f, float e[3][3]) {
#pragma clang fp contract(off)
    int i0 = faces[3 * f + 0], i1 = faces[3 * f + 1], i2 = faces[3 * f + 2];
#pragma unroll
    for (int c = 0; c < 3; ++c) {
        float a = v[3 * i0 + c], b = v[3 * i1 + c], cc = v[3 * i2 + c];
        e[0][c] = b - a;
        e[1][c] = cc - b;
        e[2][c] = a - cc;
    }
}

__global__ __launch_bounds__(256) void ec_cross_nows_kernel(
    const float* __restrict__ vertices, const int* __restrict__ faces,
    const float* __restrict__ probs, const int* __restrict__ nbrs,
    float* __restrict__ out, int F, int K) {
#pragma clang fp contract(off)
    int P = F * K;
    int stride = gridDim.x * blockDim.x;
    float acc = 0.f;
    for (int p = blockIdx.x * blockDim.x + threadIdx.x; p < P; p += stride) {
        int f = p / K;
        int nb = nbrs[p];
        float e[3][3], n[3][3];
        ec_load_edges_direct(vertices, faces, f, e);
        ec_load_edges_direct(vertices, faces, nb, n);
        int cnt = ec_count9(e, n);
        acc += probs[f] * (float)cnt;
    }
    float r = ec_block_reduce(acc);
    if (threadIdx.x == 0) atomicAdd(out, r);
}

extern "C" void kernel_launch(void* const* d_in, const int* in_sizes, int n_in,
                              void* d_out, int out_size, void* d_ws, size_t ws_size,
                              hipStream_t stream) {
    const float* vertices = (const float*)d_in[0];
    const int*   faces    = (const int*)d_in[1];
    const float* probs    = (const float*)d_in[2];
    const int*   nbrs     = (const int*)d_in[3];
    int F = in_sizes[1] / 3;
    int K = (F > 0) ? (in_sizes[3] / F) : 0;
    int P = F * K;

    size_t need = (size_t)F * 2 * sizeof(float4);
    const int GS_BLOCKS = 512;  // 512 atomics total: no atomic queue

    if (ws_size >= need && K > 0) {
        float4* recs = (float4*)d_ws;
        ec_build_kernel<<<(F + 255) / 256, 256, 0, stream>>>(vertices, faces, recs,
                                                             (float*)d_out, F);
        if ((K % 4) == 0) {
            int Q = P / 4;
            int blocks = (Q + 255) / 256; if (blocks > GS_BLOCKS) blocks = GS_BLOCKS;
            ec_diag4gs_kernel<<<blocks, 256, 0, stream>>>(recs, probs, (const int4*)nbrs,
                                                          (float*)d_out, Q, K / 4);
        } else {
            int blocks = (P + 255) / 256; if (blocks > GS_BLOCKS) blocks = GS_BLOCKS;
            ec_diag1gs_kernel<<<blocks, 256, 0, stream>>>(recs, probs, nbrs,
                                                          (float*)d_out, P, K);
        }
    } else {
        hipMemsetAsync(d_out, 0, sizeof(float), stream);
        int blocks = (P + 255) / 256; if (blocks > 2048) blocks = 2048; if (blocks < 1) blocks = 1;
        ec_cross_nows_kernel<<<blocks, 256, 0, stream>>>(vertices, faces, probs, nbrs,
                                                         (float*)d_out, F, K);
    }
}